// Round 5
// baseline (379.649 us; speedup 1.0000x reference)
//
#include <hip/hip_runtime.h>
#include <math.h>

// Problem constants (match reference)
#define B_    4
#define T_    2048
#define D_    1024
#define F_    4096
#define R_    (B_*T_)      // 8192 rows (b,t)
#define SEG_  64           // segments per time-chain
#define L_    (T_/SEG_)    // 32 steps per segment
#define DECAYF 0.9f
#define OMDF   0.1f        // 1 - decay
// Flag threshold below 0.5: the k4 fallback re-tests at exactly 0.5 in fp32,
// so flags only need NO FALSE NEGATIVES. fp8(x8-scaled) GEMM error is
// ~1e-3 RMS (6-sigma ~7e-3); margin 0.05 is ~7x worst plausible error.
#define FLAG_THRESH 0.45f

typedef __attribute__((ext_vector_type(4)))  int   i32x4;
typedef __attribute__((ext_vector_type(8)))  int   i32x8;
typedef __attribute__((ext_vector_type(16))) float f32x16;

// pack 4 floats into 4 fp8 e4m3 bytes (byte0 = first arg)
__device__ __forceinline__ int pk_fp8x4(float x, float y, float z, float w) {
    int p = 0;
    p = __builtin_amdgcn_cvt_pk_fp8_f32(x, y, p, false);  // bytes 0,1
    p = __builtin_amdgcn_cvt_pk_fp8_f32(z, w, p, true);   // bytes 2,3
    return p;
}

__device__ __forceinline__ void gload_lds16(const void* g, void* l) {
    __builtin_amdgcn_global_load_lds(
        (const __attribute__((address_space(1))) unsigned int*)g,
        (__attribute__((address_space(3))) unsigned int*)l, 16, 0, 0);
}

// ---------------------------------------------------------------------------
// KA: fused prologue. Grid-partitioned roles:
//   blocks [0, 4096):       W1 fp32 -> fp8 e4m3, values x8 (scale 2^-3 in MFMA)
//   blocks [4096, 4352):    per-segment EMA end-state (seg_sum)
//   blocks [4352, 4384):    zero the 8192 per-row spike flags
#define KA_W1_BLOCKS  4096
#define KA_SEG_BLOCKS 256
#define KA_FLAG_BLOCKS 32

__global__ __launch_bounds__(256)
void kA_prologue(const float* __restrict__ spikes,
                 const float* __restrict__ W1,
                 unsigned char* __restrict__ w_f8,
                 float* __restrict__ seg_sum,
                 unsigned int* __restrict__ flags) {
    const int bid = blockIdx.x;
    const int tid = threadIdx.x;
    if (bid < KA_W1_BLOCKS) {
        int i = bid * 256 + tid;                  // float4 index
        float4 v = ((const float4*)W1)[i];
        ((int*)w_f8)[i] = pk_fp8x4(8.f*v.x, 8.f*v.y, 8.f*v.z, 8.f*v.w);
    } else if (bid < KA_W1_BLOCKS + KA_SEG_BLOCKS) {
        int t = (bid - KA_W1_BLOCKS) * 256 + tid; // B_*SEG_*D_/4 threads
        int dg = t & (D_ / 4 - 1);
        int s = (t >> 8) & (SEG_ - 1);
        int b = t >> 14;
        const float4* sp4 = (const float4*)spikes;
        const int base = (b * T_ + s * L_) * (D_ / 4) + dg;
        float4 e = {0.f, 0.f, 0.f, 0.f};
#pragma unroll 8
        for (int k = 0; k < L_; ++k) {
            float4 x = sp4[base + k * (D_ / 4)];
            e.x = DECAYF * e.x + OMDF * x.x;
            e.y = DECAYF * e.y + OMDF * x.y;
            e.z = DECAYF * e.z + OMDF * x.z;
            e.w = DECAYF * e.w + OMDF * x.w;
        }
        ((float4*)seg_sum)[(b * SEG_ + s) * (D_ / 4) + dg] = e;
    } else {
        int i = (bid - KA_W1_BLOCKS - KA_SEG_BLOCKS) * 256 + tid;
        if (i < R_) flags[i] = 0u;
    }
}

// ---------------------------------------------------------------------------
// KB: weighted Kogge-Stone scan over the 64 segments of each (b,d) chain,
// one chain per 64-lane wave (lane = segment). start_state[s] = scan[s-1].
__global__ __launch_bounds__(256)
void kB_seg_scan(const float* __restrict__ seg_sum,
                 float* __restrict__ start_state) {
    int g = blockIdx.x * 256 + threadIdx.x;   // B_*D_*64 threads
    int s = g & 63;                           // segment = lane
    int c = g >> 6;                           // chain id: 0..B_*D_-1
    int d = c & (D_ - 1);
    int b = c >> 10;
    int idx = (b * SEG_ + s) * D_ + d;
    float v = seg_sum[idx];
    float wp = 0.0343368382f;                 // 0.9^32 (per-segment decay)
#pragma unroll
    for (int off = 1; off < SEG_; off <<= 1) {
        float u = __shfl_up(v, off, 64);
        if (s >= off) v += wp * u;
        wp *= wp;                             // w^1, w^2, w^4, ...
    }
    float pv = __shfl_up(v, 1, 64);
    start_state[idx] = (s == 0) ? 0.f : pv;
}

// ---------------------------------------------------------------------------
// KC: recompute segment-local EMA seeded with start_state; emit fp8 (x8).
__global__ __launch_bounds__(256)
void kC_ema_fp8(const float* __restrict__ spikes,
                const float* __restrict__ start_state,
                unsigned char* __restrict__ a_f8) {
    int t = blockIdx.x * 256 + threadIdx.x;            // B_*SEG_*D_/4 threads
    int dg = t & (D_ / 4 - 1);
    int s = (t >> 8) & (SEG_ - 1);
    int b = t >> 14;
    const float4* sp4 = (const float4*)spikes;
    const int base = (b * T_ + s * L_) * (D_ / 4) + dg;
    float4 e = ((const float4*)start_state)[(b * SEG_ + s) * (D_ / 4) + dg];
#pragma unroll 8
    for (int k = 0; k < L_; ++k) {
        float4 x = sp4[base + k * (D_ / 4)];
        e.x = DECAYF * e.x + OMDF * x.x;
        e.y = DECAYF * e.y + OMDF * x.y;
        e.z = DECAYF * e.z + OMDF * x.z;
        e.w = DECAYF * e.w + OMDF * x.w;
        ((int*)a_f8)[base + k * (D_ / 4)] =
            pk_fp8x4(8.f*e.x, 8.f*e.y, 8.f*e.z, 8.f*e.w);
    }
}

// ---------------------------------------------------------------------------
// K2: MX-fp8 MFMA GEMM using 32x32x64 (2x the FLOP per LDS byte vs 16x16x128;
// the LDS read pipe was the R4 structural ceiling). Uniform e8m0 scales =
// 2^-3 on both operands (values stored x8) so acc == sum a*w exactly.
// 128x128 tile, BK=64 (rows = 64 B = 4 x 16B chunks), 4 waves 2x2, each wave
// a 2x2 grid of 32x32x64 MFMAs. Swizzle: physical chunk = lc ^ ((row>>1)&3)
// -> each 16-lane quarter covers all 8 (row-parity x chunk-quad) bank groups
// at the 2-phase minimum, for staging AND frag reads (conflict-free).
// A-operand layout: row m = lane&31, k bytes [kg*32, kg*32+32), kg = lane>>5.
__global__ __launch_bounds__(256, 3)
void k2_mfma_flags(const unsigned char* __restrict__ A,   // a_f8 [R_ x D_]
                   const unsigned char* __restrict__ Bw,  // w_f8 [F_ x D_]
                   unsigned int* __restrict__ flags) {
    __shared__ __align__(16) unsigned char lA[128 * 64];
    __shared__ __align__(16) unsigned char lB[128 * 64];
    const int tid = threadIdx.x;
    const int w = tid >> 6;
    const int lane = tid & 63;
    const int m0 = blockIdx.y * 128;
    const int n0 = blockIdx.x * 128;
    const int wm = w >> 1, wn = w & 1;
    const int col = lane & 31;          // m (A) / n (B) within 32-tile
    const int kg  = lane >> 5;          // k-half: 0 or 1

    // Loop-invariant LDS byte offsets for the 8 frag reads (2 frags x lo/hi
    // per operand): row*64 + ((2*kg+d) ^ ((row>>1)&3)) * 16
    int offA[2][2], offB[2][2];
#pragma unroll
    for (int i = 0; i < 2; ++i) {
        const int ra = wm * 64 + i * 32 + col;
        const int swa = (ra >> 1) & 3;
        offA[i][0] = ra * 64 + ((2 * kg    ) ^ swa) * 16;
        offA[i][1] = ra * 64 + ((2 * kg + 1) ^ swa) * 16;
        const int rb = wn * 64 + i * 32 + col;
        const int swb = (rb >> 1) & 3;
        offB[i][0] = rb * 64 + ((2 * kg    ) ^ swb) * 16;
        offB[i][1] = rb * 64 + ((2 * kg + 1) ^ swb) * 16;
    }

    f32x16 acc[2][2] = {};

    for (int k0 = 0; k0 < D_; k0 += 64) {
        __syncthreads();   // previous iter's LDS reads must complete
        // Stage A and B tiles: 512 16B-chunks each; 2 rounds x 4 waves x 64.
#pragma unroll
        for (int r = 0; r < 2; ++r) {
            const int Ibase = r * 256 + w * 64;
            const int I = Ibase + lane;
            const int row = I >> 2;
            const int lc = (I & 3) ^ ((row >> 1) & 3);   // swizzled source chunk
            gload_lds16(&A [(size_t)(m0 + row) * D_ + k0 + lc * 16], &lA[Ibase * 16]);
            gload_lds16(&Bw[(size_t)(n0 + row) * D_ + k0 + lc * 16], &lB[Ibase * 16]);
        }
        __syncthreads();   // drains vmcnt: staged data visible

        i32x8 af[2], bf[2];
#pragma unroll
        for (int i = 0; i < 2; ++i) {
            i32x4 a0 = *(const i32x4*)&lA[offA[i][0]];
            i32x4 a1 = *(const i32x4*)&lA[offA[i][1]];
            af[i] = (i32x8){a0.x, a0.y, a0.z, a0.w, a1.x, a1.y, a1.z, a1.w};
            i32x4 b0 = *(const i32x4*)&lB[offB[i][0]];
            i32x4 b1 = *(const i32x4*)&lB[offB[i][1]];
            bf[i] = (i32x8){b0.x, b0.y, b0.z, b0.w, b1.x, b1.y, b1.z, b1.w};
        }
#pragma unroll
        for (int i = 0; i < 2; ++i)
#pragma unroll
            for (int j = 0; j < 2; ++j)
                acc[i][j] = __builtin_amdgcn_mfma_scale_f32_32x32x64_f8f6f4(
                    af[i], bf[j], acc[i][j],
                    0, 0,          // cbsz: A fmt = fp8 e4m3, blgp: B fmt = fp8
                    0, 124,        // scaleA opsel, e8m0 124 = 2^-3
                    0, 124);       // scaleB opsel, e8m0 124 = 2^-3
    }

    // Epilogue: per-row spike flags. 32x32 C/D layout (m74/m101-verified):
    // col = lane&31, row = (reg&3) + 8*(reg>>2) + 4*(lane>>5).
#pragma unroll
    for (int i = 0; i < 2; ++i) {
#pragma unroll
        for (int reg = 0; reg < 16; ++reg) {
            float mx = fmaxf(acc[i][0][reg], acc[i][1][reg]);
            if (mx > FLAG_THRESH) {
                const int rr = (reg & 3) + 8 * (reg >> 2) + 4 * kg;
                atomicOr(&flags[m0 + wm * 64 + i * 32 + rr], 1u);
            }
        }
    }
}

// ---------------------------------------------------------------------------
// K4: one block per (b,t) row. Unflagged rows (the overwhelmingly common
// case) write zeros. Flagged rows take the exact fp32 slow path, rebuilding
// the EMA row from start_state + <=32 spike rows.
__global__ __launch_bounds__(256)
void k4_output(const float* __restrict__ spikes,
               const float* __restrict__ start_state,
               const float* __restrict__ W1,
               const float* __restrict__ Wr,
               const float* __restrict__ W2,
               const unsigned int* __restrict__ flags,
               float* __restrict__ out) {
    const int row = blockIdx.x;          // 0..R_-1
    const int tid = threadIdx.x;
    float4 o = {0.f, 0.f, 0.f, 0.f};

    if (flags[row] == 0u) {              // wave-uniform branch (per block)
        *(float4*)&out[(size_t)row * D_ + tid * 4] = o;
        return;
    }

    __shared__ float se[D_];
    __shared__ float sp[D_];
    __shared__ float red[256];
    __shared__ int nspk;
    __shared__ int spk_list[256];

    const int b = row / T_;
    const int t = row % T_;
    const int seg = t / L_;
    const int off = t % L_;
    const int segbase = (b * T_ + seg * L_) * D_;

    for (int i = tid; i < D_; i += 256) {
        float e = start_state[(b * SEG_ + seg) * D_ + i];
        for (int j = 0; j <= off; ++j)
            e = DECAYF * e + OMDF * spikes[segbase + j * D_ + i];
        se[i] = e;
        sp[i] = spikes[(size_t)row * D_ + i];
    }
    if (tid == 0) nspk = 0;
    __syncthreads();

    for (int f0 = 0; f0 < F_; f0 += 256) {
        int f = f0 + tid;
        float mix = 0.f;
        for (int k = 0; k < D_; ++k) mix += se[k] * W1[(size_t)f * D_ + k];
        if (mix > 0.5f) {
            int idx = atomicAdd(&nspk, 1);
            spk_list[idx] = f;
        }
        __syncthreads();
        int n = nspk;
        for (int i = 0; i < n; ++i) {
            int fs = spk_list[i];
            float part = 0.f;
#pragma unroll
            for (int k = 0; k < 4; ++k)
                part += sp[tid * 4 + k] * Wr[(size_t)fs * D_ + tid * 4 + k];
            red[tid] = part;
            __syncthreads();
            for (int sft = 128; sft > 0; sft >>= 1) {
                if (tid < sft) red[tid] += red[tid + sft];
                __syncthreads();
            }
            float r = 1.f / (1.f + expf(-red[0]));
            __syncthreads();
            o.x += r * W2[(size_t)(tid * 4 + 0) * F_ + fs];
            o.y += r * W2[(size_t)(tid * 4 + 1) * F_ + fs];
            o.z += r * W2[(size_t)(tid * 4 + 2) * F_ + fs];
            o.w += r * W2[(size_t)(tid * 4 + 3) * F_ + fs];
        }
        __syncthreads();
        if (tid == 0) nspk = 0;
        __syncthreads();
    }
    *(float4*)&out[(size_t)row * D_ + tid * 4] = o;
}

// ---------------------------------------------------------------------------
extern "C" void kernel_launch(void* const* d_in, const int* in_sizes, int n_in,
                              void* d_out, int out_size, void* d_ws, size_t ws_size,
                              hipStream_t stream) {
    const float* spikes = (const float*)d_in[0];   // [B,T,D]
    const float* W1     = (const float*)d_in[1];   // [F,D]
    const float* W2     = (const float*)d_in[2];   // [D,F]
    const float* Wr     = (const float*)d_in[3];   // [F,D]
    float* out = (float*)d_out;                    // [B,T,D]

    // workspace layout (~14.3 MB total)
    char* ws = (char*)d_ws;
    float* seg_sum      = (float*)ws;                                // 1 MB
    float* start_state  = seg_sum + (size_t)B_ * SEG_ * D_;          // 1 MB
    unsigned int* flags = (unsigned int*)(start_state + (size_t)B_ * SEG_ * D_); // 32 KB
    unsigned char* a_f8 = (unsigned char*)(flags + R_);              // 8 MB
    unsigned char* w_f8 = a_f8 + (size_t)R_ * D_;                    // 4 MB

    kA_prologue<<<KA_W1_BLOCKS + KA_SEG_BLOCKS + KA_FLAG_BLOCKS, 256, 0, stream>>>(
        spikes, W1, w_f8, seg_sum, flags);
    kB_seg_scan<<<(B_ * D_ * 64) / 256, 256, 0, stream>>>(seg_sum, start_state);
    kC_ema_fp8<<<(B_ * SEG_ * D_ / 4) / 256, 256, 0, stream>>>(spikes, start_state, a_f8);

    dim3 g2(F_ / 128, R_ / 128);
    k2_mfma_flags<<<g2, 256, 0, stream>>>(a_f8, w_f8, flags);

    k4_output<<<R_, 256, 0, stream>>>(spikes, start_state, W1, Wr, W2, flags, out);
}

// Round 6
// 213.367 us; speedup vs baseline: 1.7793x; 1.7793x over previous
//
#include <hip/hip_runtime.h>
#include <math.h>

// Problem constants (match reference)
#define B_    4
#define T_    2048
#define D_    1024
#define F_    4096
#define R_    (B_*T_)      // 8192 rows (b,t)
#define SEG_  64           // segments per time-chain
#define L_    (T_/SEG_)    // 32 steps per segment
#define DECAYF 0.9f
#define OMDF   0.1f        // 1 - decay
// Flag threshold below 0.5: the k4 fallback re-tests at exactly 0.5 in fp32,
// so flags only need NO FALSE NEGATIVES. fp8(x8-scaled) GEMM error is
// ~1e-3 RMS (6-sigma ~7e-3); margin 0.05 is ~7x worst plausible error.
#define FLAG_THRESH 0.45f

typedef __attribute__((ext_vector_type(4)))  int   i32x4;
typedef __attribute__((ext_vector_type(8)))  int   i32x8;
typedef __attribute__((ext_vector_type(16))) float f32x16;

// pack 4 floats into 4 fp8 e4m3 bytes (byte0 = first arg)
__device__ __forceinline__ int pk_fp8x4(float x, float y, float z, float w) {
    int p = 0;
    p = __builtin_amdgcn_cvt_pk_fp8_f32(x, y, p, false);  // bytes 0,1
    p = __builtin_amdgcn_cvt_pk_fp8_f32(z, w, p, true);   // bytes 2,3
    return p;
}

__device__ __forceinline__ void gload_lds16(const void* g, void* l) {
    __builtin_amdgcn_global_load_lds(
        (const __attribute__((address_space(1))) unsigned int*)g,
        (__attribute__((address_space(3))) unsigned int*)l, 16, 0, 0);
}

// ---------------------------------------------------------------------------
// KA: fused prologue. Grid-partitioned roles:
//   blocks [0, 4096):       W1 fp32 -> fp8 e4m3, values x8 (scale 2^-3 in MFMA)
//   blocks [4096, 4352):    per-segment EMA end-state (seg_sum)
//   blocks [4352, 4384):    zero the 8192 per-row spike flags
#define KA_W1_BLOCKS  4096
#define KA_SEG_BLOCKS 256
#define KA_FLAG_BLOCKS 32

__global__ __launch_bounds__(256)
void kA_prologue(const float* __restrict__ spikes,
                 const float* __restrict__ W1,
                 unsigned char* __restrict__ w_f8,
                 float* __restrict__ seg_sum,
                 unsigned int* __restrict__ flags) {
    const int bid = blockIdx.x;
    const int tid = threadIdx.x;
    if (bid < KA_W1_BLOCKS) {
        int i = bid * 256 + tid;                  // float4 index
        float4 v = ((const float4*)W1)[i];
        ((int*)w_f8)[i] = pk_fp8x4(8.f*v.x, 8.f*v.y, 8.f*v.z, 8.f*v.w);
    } else if (bid < KA_W1_BLOCKS + KA_SEG_BLOCKS) {
        int t = (bid - KA_W1_BLOCKS) * 256 + tid; // B_*SEG_*D_/4 threads
        int dg = t & (D_ / 4 - 1);
        int s = (t >> 8) & (SEG_ - 1);
        int b = t >> 14;
        const float4* sp4 = (const float4*)spikes;
        const int base = (b * T_ + s * L_) * (D_ / 4) + dg;
        float4 e = {0.f, 0.f, 0.f, 0.f};
#pragma unroll 8
        for (int k = 0; k < L_; ++k) {
            float4 x = sp4[base + k * (D_ / 4)];
            e.x = DECAYF * e.x + OMDF * x.x;
            e.y = DECAYF * e.y + OMDF * x.y;
            e.z = DECAYF * e.z + OMDF * x.z;
            e.w = DECAYF * e.w + OMDF * x.w;
        }
        ((float4*)seg_sum)[(b * SEG_ + s) * (D_ / 4) + dg] = e;
    } else {
        int i = (bid - KA_W1_BLOCKS - KA_SEG_BLOCKS) * 256 + tid;
        if (i < R_) flags[i] = 0u;
    }
}

// ---------------------------------------------------------------------------
// KB: weighted Kogge-Stone scan over the 64 segments of each (b,d) chain,
// one chain per 64-lane wave (lane = segment). start_state[s] = scan[s-1].
__global__ __launch_bounds__(256)
void kB_seg_scan(const float* __restrict__ seg_sum,
                 float* __restrict__ start_state) {
    int g = blockIdx.x * 256 + threadIdx.x;   // B_*D_*64 threads
    int s = g & 63;                           // segment = lane
    int c = g >> 6;                           // chain id: 0..B_*D_-1
    int d = c & (D_ - 1);
    int b = c >> 10;
    int idx = (b * SEG_ + s) * D_ + d;
    float v = seg_sum[idx];
    float wp = 0.0343368382f;                 // 0.9^32 (per-segment decay)
#pragma unroll
    for (int off = 1; off < SEG_; off <<= 1) {
        float u = __shfl_up(v, off, 64);
        if (s >= off) v += wp * u;
        wp *= wp;                             // w^1, w^2, w^4, ...
    }
    float pv = __shfl_up(v, 1, 64);
    start_state[idx] = (s == 0) ? 0.f : pv;
}

// ---------------------------------------------------------------------------
// KC: recompute segment-local EMA seeded with start_state; emit fp8 (x8).
__global__ __launch_bounds__(256)
void kC_ema_fp8(const float* __restrict__ spikes,
                const float* __restrict__ start_state,
                unsigned char* __restrict__ a_f8) {
    int t = blockIdx.x * 256 + threadIdx.x;            // B_*SEG_*D_/4 threads
    int dg = t & (D_ / 4 - 1);
    int s = (t >> 8) & (SEG_ - 1);
    int b = t >> 14;
    const float4* sp4 = (const float4*)spikes;
    const int base = (b * T_ + s * L_) * (D_ / 4) + dg;
    float4 e = ((const float4*)start_state)[(b * SEG_ + s) * (D_ / 4) + dg];
#pragma unroll 8
    for (int k = 0; k < L_; ++k) {
        float4 x = sp4[base + k * (D_ / 4)];
        e.x = DECAYF * e.x + OMDF * x.x;
        e.y = DECAYF * e.y + OMDF * x.y;
        e.z = DECAYF * e.z + OMDF * x.z;
        e.w = DECAYF * e.w + OMDF * x.w;
        ((int*)a_f8)[base + k * (D_ / 4)] =
            pk_fp8x4(8.f*e.x, 8.f*e.y, 8.f*e.z, 8.f*e.w);
    }
}

// ---------------------------------------------------------------------------
// K2: MX-fp8 MFMA GEMM using 32x32x64 (2x the FLOP per LDS byte vs 16x16x128;
// the LDS read pipe was the R4 structural ceiling). Uniform e8m0 scales =
// 2^-3 on both operands (values stored x8) so acc == sum a*w exactly.
// 128x128 tile, BK=64 (rows = 64 B = 4 x 16B chunks), 4 waves 2x2, each wave
// a 2x2 grid of 32x32x64 MFMAs. Swizzle: physical chunk = lc ^ ((row>>1)&3)
// -> each 16-lane quarter covers all 8 (row-parity x chunk-quad) bank groups
// at the 2-phase minimum, for staging AND frag reads.
// NOTE: plain __launch_bounds__(256). R5's (256,3) min-waves floor capped
// VGPRs at ~160 and the allocator SPILLED THE ACCUMULATORS to scratch
// (VGPR_Count 84, WRITE_SIZE 557 MB, 250+ us). Never floor-cap this kernel.
__global__ __launch_bounds__(256)
void k2_mfma_flags(const unsigned char* __restrict__ A,   // a_f8 [R_ x D_]
                   const unsigned char* __restrict__ Bw,  // w_f8 [F_ x D_]
                   unsigned int* __restrict__ flags) {
    __shared__ __align__(16) unsigned char lA[128 * 64];
    __shared__ __align__(16) unsigned char lB[128 * 64];
    const int tid = threadIdx.x;
    const int w = tid >> 6;
    const int lane = tid & 63;
    const int m0 = blockIdx.y * 128;
    const int n0 = blockIdx.x * 128;
    const int wm = w >> 1, wn = w & 1;
    const int col = lane & 31;          // m (A) / n (B) within 32-tile
    const int kg  = lane >> 5;          // k-half: 0 or 1

    // Loop-invariant LDS byte offsets for the 8 frag reads (2 frags x lo/hi
    // per operand): row*64 + ((2*kg+d) ^ ((row>>1)&3)) * 16
    int offA[2][2], offB[2][2];
#pragma unroll
    for (int i = 0; i < 2; ++i) {
        const int ra = wm * 64 + i * 32 + col;
        const int swa = (ra >> 1) & 3;
        offA[i][0] = ra * 64 + ((2 * kg    ) ^ swa) * 16;
        offA[i][1] = ra * 64 + ((2 * kg + 1) ^ swa) * 16;
        const int rb = wn * 64 + i * 32 + col;
        const int swb = (rb >> 1) & 3;
        offB[i][0] = rb * 64 + ((2 * kg    ) ^ swb) * 16;
        offB[i][1] = rb * 64 + ((2 * kg + 1) ^ swb) * 16;
    }

    f32x16 acc[2][2] = {};

    for (int k0 = 0; k0 < D_; k0 += 64) {
        __syncthreads();   // previous iter's LDS reads must complete
        // Stage A and B tiles: 512 16B-chunks each; 2 rounds x 4 waves x 64.
#pragma unroll
        for (int r = 0; r < 2; ++r) {
            const int Ibase = r * 256 + w * 64;
            const int I = Ibase + lane;
            const int row = I >> 2;
            const int lc = (I & 3) ^ ((row >> 1) & 3);   // swizzled source chunk
            gload_lds16(&A [(size_t)(m0 + row) * D_ + k0 + lc * 16], &lA[Ibase * 16]);
            gload_lds16(&Bw[(size_t)(n0 + row) * D_ + k0 + lc * 16], &lB[Ibase * 16]);
        }
        __syncthreads();   // drains vmcnt: staged data visible

        i32x8 af[2], bf[2];
#pragma unroll
        for (int i = 0; i < 2; ++i) {
            i32x4 a0 = *(const i32x4*)&lA[offA[i][0]];
            i32x4 a1 = *(const i32x4*)&lA[offA[i][1]];
            af[i] = (i32x8){a0.x, a0.y, a0.z, a0.w, a1.x, a1.y, a1.z, a1.w};
            i32x4 b0 = *(const i32x4*)&lB[offB[i][0]];
            i32x4 b1 = *(const i32x4*)&lB[offB[i][1]];
            bf[i] = (i32x8){b0.x, b0.y, b0.z, b0.w, b1.x, b1.y, b1.z, b1.w};
        }
#pragma unroll
        for (int i = 0; i < 2; ++i)
#pragma unroll
            for (int j = 0; j < 2; ++j)
                acc[i][j] = __builtin_amdgcn_mfma_scale_f32_32x32x64_f8f6f4(
                    af[i], bf[j], acc[i][j],
                    0, 0,          // cbsz: A fmt = fp8 e4m3, blgp: B fmt = fp8
                    0, 124,        // scaleA opsel, e8m0 124 = 2^-3
                    0, 124);       // scaleB opsel, e8m0 124 = 2^-3
    }

    // Epilogue: per-row spike flags. 32x32 C/D layout (m74/m101-verified):
    // col = lane&31, row = (reg&3) + 8*(reg>>2) + 4*(lane>>5).
#pragma unroll
    for (int i = 0; i < 2; ++i) {
#pragma unroll
        for (int reg = 0; reg < 16; ++reg) {
            float mx = fmaxf(acc[i][0][reg], acc[i][1][reg]);
            if (mx > FLAG_THRESH) {
                const int rr = (reg & 3) + 8 * (reg >> 2) + 4 * kg;
                atomicOr(&flags[m0 + wm * 64 + i * 32 + rr], 1u);
            }
        }
    }
}

// ---------------------------------------------------------------------------
// K4: one block per (b,t) row. Unflagged rows (the overwhelmingly common
// case) write zeros. Flagged rows take the exact fp32 slow path, rebuilding
// the EMA row from start_state + <=32 spike rows.
__global__ __launch_bounds__(256)
void k4_output(const float* __restrict__ spikes,
               const float* __restrict__ start_state,
               const float* __restrict__ W1,
               const float* __restrict__ Wr,
               const float* __restrict__ W2,
               const unsigned int* __restrict__ flags,
               float* __restrict__ out) {
    const int row = blockIdx.x;          // 0..R_-1
    const int tid = threadIdx.x;
    float4 o = {0.f, 0.f, 0.f, 0.f};

    if (flags[row] == 0u) {              // wave-uniform branch (per block)
        *(float4*)&out[(size_t)row * D_ + tid * 4] = o;
        return;
    }

    __shared__ float se[D_];
    __shared__ float sp[D_];
    __shared__ float red[256];
    __shared__ int nspk;
    __shared__ int spk_list[256];

    const int b = row / T_;
    const int t = row % T_;
    const int seg = t / L_;
    const int off = t % L_;
    const int segbase = (b * T_ + seg * L_) * D_;

    for (int i = tid; i < D_; i += 256) {
        float e = start_state[(b * SEG_ + seg) * D_ + i];
        for (int j = 0; j <= off; ++j)
            e = DECAYF * e + OMDF * spikes[segbase + j * D_ + i];
        se[i] = e;
        sp[i] = spikes[(size_t)row * D_ + i];
    }
    if (tid == 0) nspk = 0;
    __syncthreads();

    for (int f0 = 0; f0 < F_; f0 += 256) {
        int f = f0 + tid;
        float mix = 0.f;
        for (int k = 0; k < D_; ++k) mix += se[k] * W1[(size_t)f * D_ + k];
        if (mix > 0.5f) {
            int idx = atomicAdd(&nspk, 1);
            spk_list[idx] = f;
        }
        __syncthreads();
        int n = nspk;
        for (int i = 0; i < n; ++i) {
            int fs = spk_list[i];
            float part = 0.f;
#pragma unroll
            for (int k = 0; k < 4; ++k)
                part += sp[tid * 4 + k] * Wr[(size_t)fs * D_ + tid * 4 + k];
            red[tid] = part;
            __syncthreads();
            for (int sft = 128; sft > 0; sft >>= 1) {
                if (tid < sft) red[tid] += red[tid + sft];
                __syncthreads();
            }
            float r = 1.f / (1.f + expf(-red[0]));
            __syncthreads();
            o.x += r * W2[(size_t)(tid * 4 + 0) * F_ + fs];
            o.y += r * W2[(size_t)(tid * 4 + 1) * F_ + fs];
            o.z += r * W2[(size_t)(tid * 4 + 2) * F_ + fs];
            o.w += r * W2[(size_t)(tid * 4 + 3) * F_ + fs];
        }
        __syncthreads();
        if (tid == 0) nspk = 0;
        __syncthreads();
    }
    *(float4*)&out[(size_t)row * D_ + tid * 4] = o;
}

// ---------------------------------------------------------------------------
extern "C" void kernel_launch(void* const* d_in, const int* in_sizes, int n_in,
                              void* d_out, int out_size, void* d_ws, size_t ws_size,
                              hipStream_t stream) {
    const float* spikes = (const float*)d_in[0];   // [B,T,D]
    const float* W1     = (const float*)d_in[1];   // [F,D]
    const float* W2     = (const float*)d_in[2];   // [D,F]
    const float* Wr     = (const float*)d_in[3];   // [F,D]
    float* out = (float*)d_out;                    // [B,T,D]

    // workspace layout (~14.3 MB total)
    char* ws = (char*)d_ws;
    float* seg_sum      = (float*)ws;                                // 1 MB
    float* start_state  = seg_sum + (size_t)B_ * SEG_ * D_;          // 1 MB
    unsigned int* flags = (unsigned int*)(start_state + (size_t)B_ * SEG_ * D_); // 32 KB
    unsigned char* a_f8 = (unsigned char*)(flags + R_);              // 8 MB
    unsigned char* w_f8 = a_f8 + (size_t)R_ * D_;                    // 4 MB

    kA_prologue<<<KA_W1_BLOCKS + KA_SEG_BLOCKS + KA_FLAG_BLOCKS, 256, 0, stream>>>(
        spikes, W1, w_f8, seg_sum, flags);
    kB_seg_scan<<<(B_ * D_ * 64) / 256, 256, 0, stream>>>(seg_sum, start_state);
    kC_ema_fp8<<<(B_ * SEG_ * D_ / 4) / 256, 256, 0, stream>>>(spikes, start_state, a_f8);

    dim3 g2(F_ / 128, R_ / 128);
    k2_mfma_flags<<<g2, 256, 0, stream>>>(a_f8, w_f8, flags);

    k4_output<<<R_, 256, 0, stream>>>(spikes, start_state, W1, Wr, W2, flags, out);
}

// Round 7
// 206.681 us; speedup vs baseline: 1.8369x; 1.0323x over previous
//
#include <hip/hip_runtime.h>
#include <math.h>

// Problem constants (match reference)
#define B_    4
#define T_    2048
#define D_    1024
#define F_    4096
#define R_    (B_*T_)      // 8192 rows (b,t)
#define SEG_  64           // segments per time-chain
#define L_    (T_/SEG_)    // 32 steps per segment
#define DECAYF 0.9f
#define OMDF   0.1f        // 1 - decay
// Flag threshold below 0.5: the k4 fallback re-tests at exactly 0.5 in fp32,
// so flags only need NO FALSE NEGATIVES. fp8(x8-scaled) GEMM error is
// ~1e-3 RMS (6-sigma ~7e-3); margin 0.05 is ~7x worst plausible error.
#define FLAG_THRESH 0.45f

typedef __attribute__((ext_vector_type(4)))  int   i32x4;
typedef __attribute__((ext_vector_type(8)))  int   i32x8;
typedef __attribute__((ext_vector_type(16))) float f32x16;

// pack 4 floats into 4 fp8 e4m3 bytes (byte0 = first arg)
__device__ __forceinline__ int pk_fp8x4(float x, float y, float z, float w) {
    int p = 0;
    p = __builtin_amdgcn_cvt_pk_fp8_f32(x, y, p, false);  // bytes 0,1
    p = __builtin_amdgcn_cvt_pk_fp8_f32(z, w, p, true);   // bytes 2,3
    return p;
}

// ---------------------------------------------------------------------------
// KA: fused prologue. Grid-partitioned roles:
//   blocks [0, 4096):       W1 fp32 -> fp8 e4m3, values x8 (scale 2^-3 in MFMA)
//   blocks [4096, 4352):    per-segment EMA end-state (seg_sum)
//   blocks [4352, 4384):    zero the 8192 per-row spike flags
#define KA_W1_BLOCKS  4096
#define KA_SEG_BLOCKS 256
#define KA_FLAG_BLOCKS 32

__global__ __launch_bounds__(256)
void kA_prologue(const float* __restrict__ spikes,
                 const float* __restrict__ W1,
                 unsigned char* __restrict__ w_f8,
                 float* __restrict__ seg_sum,
                 unsigned int* __restrict__ flags) {
    const int bid = blockIdx.x;
    const int tid = threadIdx.x;
    if (bid < KA_W1_BLOCKS) {
        int i = bid * 256 + tid;                  // float4 index
        float4 v = ((const float4*)W1)[i];
        ((int*)w_f8)[i] = pk_fp8x4(8.f*v.x, 8.f*v.y, 8.f*v.z, 8.f*v.w);
    } else if (bid < KA_W1_BLOCKS + KA_SEG_BLOCKS) {
        int t = (bid - KA_W1_BLOCKS) * 256 + tid; // B_*SEG_*D_/4 threads
        int dg = t & (D_ / 4 - 1);
        int s = (t >> 8) & (SEG_ - 1);
        int b = t >> 14;
        const float4* sp4 = (const float4*)spikes;
        const int base = (b * T_ + s * L_) * (D_ / 4) + dg;
        float4 e = {0.f, 0.f, 0.f, 0.f};
#pragma unroll 8
        for (int k = 0; k < L_; ++k) {
            float4 x = sp4[base + k * (D_ / 4)];
            e.x = DECAYF * e.x + OMDF * x.x;
            e.y = DECAYF * e.y + OMDF * x.y;
            e.z = DECAYF * e.z + OMDF * x.z;
            e.w = DECAYF * e.w + OMDF * x.w;
        }
        ((float4*)seg_sum)[(b * SEG_ + s) * (D_ / 4) + dg] = e;
    } else {
        int i = (bid - KA_W1_BLOCKS - KA_SEG_BLOCKS) * 256 + tid;
        if (i < R_) flags[i] = 0u;
    }
}

// ---------------------------------------------------------------------------
// KB: weighted Kogge-Stone scan over the 64 segments of each (b,d) chain,
// one chain per 64-lane wave (lane = segment). start_state[s] = scan[s-1].
__global__ __launch_bounds__(256)
void kB_seg_scan(const float* __restrict__ seg_sum,
                 float* __restrict__ start_state) {
    int g = blockIdx.x * 256 + threadIdx.x;   // B_*D_*64 threads
    int s = g & 63;                           // segment = lane
    int c = g >> 6;                           // chain id: 0..B_*D_-1
    int d = c & (D_ - 1);
    int b = c >> 10;
    int idx = (b * SEG_ + s) * D_ + d;
    float v = seg_sum[idx];
    float wp = 0.0343368382f;                 // 0.9^32 (per-segment decay)
#pragma unroll
    for (int off = 1; off < SEG_; off <<= 1) {
        float u = __shfl_up(v, off, 64);
        if (s >= off) v += wp * u;
        wp *= wp;                             // w^1, w^2, w^4, ...
    }
    float pv = __shfl_up(v, 1, 64);
    start_state[idx] = (s == 0) ? 0.f : pv;
}

// ---------------------------------------------------------------------------
// KC: recompute segment-local EMA seeded with start_state; emit fp8 (x8).
__global__ __launch_bounds__(256)
void kC_ema_fp8(const float* __restrict__ spikes,
                const float* __restrict__ start_state,
                unsigned char* __restrict__ a_f8) {
    int t = blockIdx.x * 256 + threadIdx.x;            // B_*SEG_*D_/4 threads
    int dg = t & (D_ / 4 - 1);
    int s = (t >> 8) & (SEG_ - 1);
    int b = t >> 14;
    const float4* sp4 = (const float4*)spikes;
    const int base = (b * T_ + s * L_) * (D_ / 4) + dg;
    float4 e = ((const float4*)start_state)[(b * SEG_ + s) * (D_ / 4) + dg];
#pragma unroll 8
    for (int k = 0; k < L_; ++k) {
        float4 x = sp4[base + k * (D_ / 4)];
        e.x = DECAYF * e.x + OMDF * x.x;
        e.y = DECAYF * e.y + OMDF * x.y;
        e.z = DECAYF * e.z + OMDF * x.z;
        e.w = DECAYF * e.w + OMDF * x.w;
        ((int*)a_f8)[base + k * (D_ / 4)] =
            pk_fp8x4(8.f*e.x, 8.f*e.y, 8.f*e.z, 8.f*e.w);
    }
}

// ---------------------------------------------------------------------------
// K2: MX-fp8 MFMA GEMM, 32x32x64, SOFTWARE-PIPELINED K-loop.
// R6 post-mortem: the global_load_lds + __syncthreads structure serializes
// load latency vs compute (MfmaUtil 16.7%, 2 blocks/CU). Here: register
// prefetch of tile k+1 (4 global_load_dwordx4/thread) overlaps the MFMA
// phase of tile k; double-buffered LDS (32 KB total); raw s_barrier +
// explicit lgkmcnt(0) drains instead of __syncthreads (whose compiler
// lowering drains vmcnt(0), killing the prefetch — m99/m100 lesson).
// Safety: each wave's frag ds_reads are lgkm-drained before its MFMAs
// (register dependency), hence before its barrier -> buffer p is safe to
// overwrite in the next step. ds_write's own vmcnt wait on the prefetched
// regs lands after the MFMA phase = latency hidden.
// NOTE: plain __launch_bounds__(256). R5's (256,3) floor spilled the
// accumulators to scratch (WRITE_SIZE 557 MB). Never floor-cap this kernel.
__global__ __launch_bounds__(256)
void k2_mfma_flags(const unsigned char* __restrict__ A,   // a_f8 [R_ x D_]
                   const unsigned char* __restrict__ Bw,  // w_f8 [F_ x D_]
                   unsigned int* __restrict__ flags) {
    __shared__ __align__(16) unsigned char lA[2][128 * 64];
    __shared__ __align__(16) unsigned char lB[2][128 * 64];
    const int tid = threadIdx.x;
    const int w = tid >> 6;
    const int lane = tid & 63;
    const int m0 = blockIdx.y * 128;
    const int n0 = blockIdx.x * 128;
    const int wm = w >> 1, wn = w & 1;
    const int col = lane & 31;          // m (A) / n (B) within 32-tile
    const int kg  = lane >> 5;          // k-half: 0 or 1

    // Staging: 512 16B-chunks per array per tile; thread t owns chunks
    // I0 = t and I1 = t + 256. row = I>>2, logical chunk = I&3.
    const int r0 = tid >> 2, cs = tid & 3;
    const int r1 = r0 + 64;
    const size_t gA0 = (size_t)(m0 + r0) * D_ + cs * 16;
    const size_t gA1 = (size_t)(m0 + r1) * D_ + cs * 16;
    const size_t gB0 = (size_t)(n0 + r0) * D_ + cs * 16;
    const size_t gB1 = (size_t)(n0 + r1) * D_ + cs * 16;
    // LDS dest offsets (same swizzle as frag reads: chunk ^= (row>>1)&3)
    const int ld0 = r0 * 64 + ((cs ^ ((r0 >> 1) & 3)) * 16);
    const int ld1 = r1 * 64 + ((cs ^ ((r1 >> 1) & 3)) * 16);

    // Loop-invariant frag-read offsets (within one buffer):
    int offA[2][2], offB[2][2];
#pragma unroll
    for (int i = 0; i < 2; ++i) {
        const int ra = wm * 64 + i * 32 + col;
        const int swa = (ra >> 1) & 3;
        offA[i][0] = ra * 64 + ((2 * kg    ) ^ swa) * 16;
        offA[i][1] = ra * 64 + ((2 * kg + 1) ^ swa) * 16;
        const int rb = wn * 64 + i * 32 + col;
        const int swb = (rb >> 1) & 3;
        offB[i][0] = rb * 64 + ((2 * kg    ) ^ swb) * 16;
        offB[i][1] = rb * 64 + ((2 * kg + 1) ^ swb) * 16;
    }

    f32x16 acc[2][2] = {};

    // Prologue: stage tile k=0 into buffer 0.
    {
        i32x4 sa0 = *(const i32x4*)(A  + gA0);
        i32x4 sa1 = *(const i32x4*)(A  + gA1);
        i32x4 sb0 = *(const i32x4*)(Bw + gB0);
        i32x4 sb1 = *(const i32x4*)(Bw + gB1);
        *(i32x4*)&lA[0][ld0] = sa0;
        *(i32x4*)&lA[0][ld1] = sa1;
        *(i32x4*)&lB[0][ld0] = sb0;
        *(i32x4*)&lB[0][ld1] = sb1;
        asm volatile("s_waitcnt lgkmcnt(0)" ::: "memory");
        asm volatile("s_barrier" ::: "memory");
    }

#define K2_STEP(PBUF, NBUF, KNEXT)                                          \
    {                                                                       \
        i32x4 na0 = *(const i32x4*)(A  + gA0 + (KNEXT));                    \
        i32x4 na1 = *(const i32x4*)(A  + gA1 + (KNEXT));                    \
        i32x4 nb0 = *(const i32x4*)(Bw + gB0 + (KNEXT));                    \
        i32x4 nb1 = *(const i32x4*)(Bw + gB1 + (KNEXT));                    \
        i32x8 af[2], bfr[2];                                                \
        _Pragma("unroll")                                                   \
        for (int i = 0; i < 2; ++i) {                                       \
            i32x4 a0 = *(const i32x4*)&lA[PBUF][offA[i][0]];                \
            i32x4 a1 = *(const i32x4*)&lA[PBUF][offA[i][1]];                \
            af[i] = (i32x8){a0.x, a0.y, a0.z, a0.w, a1.x, a1.y, a1.z, a1.w};\
            i32x4 b0 = *(const i32x4*)&lB[PBUF][offB[i][0]];                \
            i32x4 b1 = *(const i32x4*)&lB[PBUF][offB[i][1]];                \
            bfr[i] = (i32x8){b0.x, b0.y, b0.z, b0.w, b1.x, b1.y, b1.z, b1.w};\
        }                                                                   \
        _Pragma("unroll")                                                   \
        for (int i = 0; i < 2; ++i)                                         \
            _Pragma("unroll")                                               \
            for (int j = 0; j < 2; ++j)                                     \
                acc[i][j] = __builtin_amdgcn_mfma_scale_f32_32x32x64_f8f6f4(\
                    af[i], bfr[j], acc[i][j], 0, 0, 0, 124, 0, 124);        \
        *(i32x4*)&lA[NBUF][ld0] = na0;                                      \
        *(i32x4*)&lA[NBUF][ld1] = na1;                                      \
        *(i32x4*)&lB[NBUF][ld0] = nb0;                                      \
        *(i32x4*)&lB[NBUF][ld1] = nb1;                                      \
        asm volatile("s_waitcnt lgkmcnt(0)" ::: "memory");                  \
        asm volatile("s_barrier" ::: "memory");                            \
    }

    // 16 K-steps of 64, unrolled x2 so buffer index is compile-time.
    // Step at k reads buf p (holds tile k), stages tile k+64 into buf 1-p.
    // Final step stages a wrapped (unused) tile — uniform code, no branch.
    for (int k0 = 0; k0 < D_; k0 += 128) {
        K2_STEP(0, 1, (size_t)(k0 + 64));
        K2_STEP(1, 0, (size_t)((k0 + 128) & (D_ - 1)));
    }
#undef K2_STEP

    // Epilogue: per-row spike flags. 32x32 C/D layout (m74/m101-verified):
    // col = lane&31, row = (reg&3) + 8*(reg>>2) + 4*(lane>>5).
#pragma unroll
    for (int i = 0; i < 2; ++i) {
#pragma unroll
        for (int reg = 0; reg < 16; ++reg) {
            float mx = fmaxf(acc[i][0][reg], acc[i][1][reg]);
            if (mx > FLAG_THRESH) {
                const int rr = (reg & 3) + 8 * (reg >> 2) + 4 * kg;
                atomicOr(&flags[m0 + wm * 64 + i * 32 + rr], 1u);
            }
        }
    }
}

// ---------------------------------------------------------------------------
// K4: one block per (b,t) row. Unflagged rows (the overwhelmingly common
// case) write zeros. Flagged rows take the exact fp32 slow path, rebuilding
// the EMA row from start_state + <=32 spike rows.
__global__ __launch_bounds__(256)
void k4_output(const float* __restrict__ spikes,
               const float* __restrict__ start_state,
               const float* __restrict__ W1,
               const float* __restrict__ Wr,
               const float* __restrict__ W2,
               const unsigned int* __restrict__ flags,
               float* __restrict__ out) {
    const int row = blockIdx.x;          // 0..R_-1
    const int tid = threadIdx.x;
    float4 o = {0.f, 0.f, 0.f, 0.f};

    if (flags[row] == 0u) {              // wave-uniform branch (per block)
        *(float4*)&out[(size_t)row * D_ + tid * 4] = o;
        return;
    }

    __shared__ float se[D_];
    __shared__ float sp[D_];
    __shared__ float red[256];
    __shared__ int nspk;
    __shared__ int spk_list[256];

    const int b = row / T_;
    const int t = row % T_;
    const int seg = t / L_;
    const int off = t % L_;
    const int segbase = (b * T_ + seg * L_) * D_;

    for (int i = tid; i < D_; i += 256) {
        float e = start_state[(b * SEG_ + seg) * D_ + i];
        for (int j = 0; j <= off; ++j)
            e = DECAYF * e + OMDF * spikes[segbase + j * D_ + i];
        se[i] = e;
        sp[i] = spikes[(size_t)row * D_ + i];
    }
    if (tid == 0) nspk = 0;
    __syncthreads();

    for (int f0 = 0; f0 < F_; f0 += 256) {
        int f = f0 + tid;
        float mix = 0.f;
        for (int k = 0; k < D_; ++k) mix += se[k] * W1[(size_t)f * D_ + k];
        if (mix > 0.5f) {
            int idx = atomicAdd(&nspk, 1);
            spk_list[idx] = f;
        }
        __syncthreads();
        int n = nspk;
        for (int i = 0; i < n; ++i) {
            int fs = spk_list[i];
            float part = 0.f;
#pragma unroll
            for (int k = 0; k < 4; ++k)
                part += sp[tid * 4 + k] * Wr[(size_t)fs * D_ + tid * 4 + k];
            red[tid] = part;
            __syncthreads();
            for (int sft = 128; sft > 0; sft >>= 1) {
                if (tid < sft) red[tid] += red[tid + sft];
                __syncthreads();
            }
            float r = 1.f / (1.f + expf(-red[0]));
            __syncthreads();
            o.x += r * W2[(size_t)(tid * 4 + 0) * F_ + fs];
            o.y += r * W2[(size_t)(tid * 4 + 1) * F_ + fs];
            o.z += r * W2[(size_t)(tid * 4 + 2) * F_ + fs];
            o.w += r * W2[(size_t)(tid * 4 + 3) * F_ + fs];
        }
        __syncthreads();
        if (tid == 0) nspk = 0;
        __syncthreads();
    }
    *(float4*)&out[(size_t)row * D_ + tid * 4] = o;
}

// ---------------------------------------------------------------------------
extern "C" void kernel_launch(void* const* d_in, const int* in_sizes, int n_in,
                              void* d_out, int out_size, void* d_ws, size_t ws_size,
                              hipStream_t stream) {
    const float* spikes = (const float*)d_in[0];   // [B,T,D]
    const float* W1     = (const float*)d_in[1];   // [F,D]
    const float* W2     = (const float*)d_in[2];   // [D,F]
    const float* Wr     = (const float*)d_in[3];   // [F,D]
    float* out = (float*)d_out;                    // [B,T,D]

    // workspace layout (~14.3 MB total)
    char* ws = (char*)d_ws;
    float* seg_sum      = (float*)ws;                                // 1 MB
    float* start_state  = seg_sum + (size_t)B_ * SEG_ * D_;          // 1 MB
    unsigned int* flags = (unsigned int*)(start_state + (size_t)B_ * SEG_ * D_); // 32 KB
    unsigned char* a_f8 = (unsigned char*)(flags + R_);              // 8 MB
    unsigned char* w_f8 = a_f8 + (size_t)R_ * D_;                    // 4 MB

    kA_prologue<<<KA_W1_BLOCKS + KA_SEG_BLOCKS + KA_FLAG_BLOCKS, 256, 0, stream>>>(
        spikes, W1, w_f8, seg_sum, flags);
    kB_seg_scan<<<(B_ * D_ * 64) / 256, 256, 0, stream>>>(seg_sum, start_state);
    kC_ema_fp8<<<(B_ * SEG_ * D_ / 4) / 256, 256, 0, stream>>>(spikes, start_state, a_f8);

    dim3 g2(F_ / 128, R_ / 128);
    k2_mfma_flags<<<g2, 256, 0, stream>>>(a_f8, w_f8, flags);

    k4_output<<<R_, 256, 0, stream>>>(spikes, start_state, W1, Wr, W2, flags, out);
}